// Round 1
// baseline (773.660 us; speedup 1.0000x reference)
//
#include <hip/hip_runtime.h>
#include <hip/hip_bf16.h>

// Problem: B=1024, L=160, D=300.  All inputs fp32; outputs (proj_T, HCD) fp32.
// Algebra: kT/qCD/kCD linears eliminated via precomputed W^T W products.
//   projT = T @ Wproj^T + b          (bf16 MFMA GEMM, out fp32 -> d_out)
//   pCD   = CD @ Wproj^T + b         (bf16, padded stride 320, col300 = 1)
//   meanT = mean_l projT ; vT = P meanT + p0 ; cT = g.meanT + c1
//   ZT[b,j] = sigmoid(vT . projT_j + cT)
//   Y = pCD @ MaugT^T    (K=320 augmented: carries Wq^T Wk /sqrt_d + u,w,c0)
//   S = Y @ pCD^T  (= alphaCD incl. all bias terms)
//   s_i = sum_j sigmoid(S_ij) * ZT_j * W3_j ; alpha = softmax_i(s)
//   HCD[i,:] = alpha_i * pCD[i,:]

typedef __attribute__((ext_vector_type(8))) short short8;
typedef __attribute__((ext_vector_type(4))) float f32x4;

#define DP 320

__device__ __forceinline__ unsigned short f2bf(float x) {
  unsigned int u = __builtin_bit_cast(unsigned int, x);
  u += 0x7FFFu + ((u >> 16) & 1u);
  return (unsigned short)(u >> 16);
}
__device__ __forceinline__ float bf2f(unsigned short h) {
  unsigned int u = ((unsigned int)h) << 16;
  return __builtin_bit_cast(float, u);
}
__device__ __forceinline__ void gload16(const void* g, void* l) {
  __builtin_amdgcn_global_load_lds(
      (const __attribute__((address_space(1))) unsigned int*)g,
      (__attribute__((address_space(3))) unsigned int*)l, 16, 0, 0);
}
__device__ __forceinline__ float sigm(float x) { return 1.0f / (1.0f + __expf(-x)); }

// ---- Wb[n][k] = bf16(Wproj[n][k]), zero-padded to 320x320 --------------------
__global__ void wb_k(const float* __restrict__ W, unsigned short* __restrict__ Wb) {
  int n = blockIdx.x, k = threadIdx.x;
  unsigned short v = 0;
  if (n < 300 && k < 300) v = f2bf(W[n * 300 + k]);
  Wb[n * DP + k] = v;
}

// ---- out[n][c] = scale * sum_o A(c,o)*B(n,o), A col c of Wa (c==300 -> ba),
//      B col n of Wc (n==300 -> bc). 320x320, zero outside. ------------------
__global__ void crossdot_k(const float* __restrict__ Wa, const float* __restrict__ ba,
                           const float* __restrict__ Wc, const float* __restrict__ bc,
                           unsigned short* __restrict__ out_h, float* __restrict__ out_f,
                           float scale) {
  int n = blockIdx.x, c = threadIdx.x;
  float v = 0.f;
  if (n <= 300 && c <= 300) {
    for (int o = 0; o < 300; ++o) {
      float a = (c < 300) ? Wa[o * 300 + c] : ba[o];
      float b = (n < 300) ? Wc[o * 300 + n] : bc[o];
      v += a * b;
    }
    v *= scale;
  }
  if (out_h) out_h[n * DP + c] = f2bf(v);
  else       out_f[n * DP + c] = v;
}

// ---- main GEMM: (163840 x 300|320) @ Bsrc[320][320] -> 163840 x 320 ---------
// MODE 0: A fp32 (stride 300, zero-pad K>=300), out fp32 stride 300 (+bias)
// MODE 1: same A, out bf16 stride 320; col300=1.0, col>300=0 (+bias)
// MODE 2: A bf16 (stride 320, K=320 full), out bf16 stride 320; col<=300 acc
template<int MODE>
__global__ __launch_bounds__(512)
void gemm_k(const float* __restrict__ Af, const unsigned short* __restrict__ Ah,
            const unsigned short* __restrict__ Bsrc, const float* __restrict__ bias,
            float* __restrict__ Of, unsigned short* __restrict__ Oh) {
  __shared__ __align__(16) unsigned short As[2][256 * 32];
  __shared__ __align__(16) unsigned short Bs[2][160 * 32];
  const int tid = threadIdx.x;
  const int wid = tid >> 6, lane = tid & 63;
  const long m0 = (long)blockIdx.y * 256;
  const int n0 = blockIdx.x * 160;

  f32x4 acc[4][5];
#pragma unroll
  for (int i = 0; i < 4; ++i)
#pragma unroll
    for (int j = 0; j < 5; ++j) acc[i][j] = (f32x4){0.f, 0.f, 0.f, 0.f};

  auto stageA = [&](int buf, int k0) {
    if (MODE < 2) {
#pragma unroll
      for (int it = 0; it < 2; ++it) {
        const int row = (tid >> 2) + it * 128;
        const int cg = (tid & 3) * 8;
        const float* p = Af + (m0 + row) * 300 + k0 + cg;
        short8 h;
        if (k0 + cg + 7 < 300) {
          f32x4 x0 = *(const f32x4*)p;
          f32x4 x1 = *(const f32x4*)(p + 4);
#pragma unroll
          for (int j = 0; j < 4; ++j) {
            h[j] = (short)f2bf(x0[j]);
            h[j + 4] = (short)f2bf(x1[j]);
          }
        } else {
#pragma unroll
          for (int j = 0; j < 8; ++j) {
            float v = (k0 + cg + j < 300) ? p[j] : 0.f;
            h[j] = (short)f2bf(v);
          }
        }
        *(short8*)&As[buf][row * 32 + cg] = h;
      }
    } else {
#pragma unroll
      for (int c = 0; c < 2; ++c) {
        int ch = wid + c * 8;
        int f = ch * 512 + lane * 8;
        gload16(Ah + (m0 + (f >> 5)) * DP + k0 + (f & 31), &As[buf][ch * 512]);
      }
    }
  };
  auto stageB = [&](int buf, int k0) {
    {
      int f = wid * 512 + lane * 8;
      gload16(Bsrc + (n0 + (f >> 5)) * DP + k0 + (f & 31), &Bs[buf][wid * 512]);
    }
    if (wid < 2) {
      int ch = wid + 8;
      int f = ch * 512 + lane * 8;
      gload16(Bsrc + (n0 + (f >> 5)) * DP + k0 + (f & 31), &Bs[buf][ch * 512]);
    }
  };

  stageA(0, 0);
  stageB(0, 0);
  __syncthreads();
  int buf = 0;
  const int rm = (wid >> 1) * 64, cn = (wid & 1) * 80;
  const int lr = lane & 15, lk = (lane >> 4) * 8;
  for (int kc = 0; kc < 10; ++kc) {
    if (kc < 9) { stageA(buf ^ 1, (kc + 1) * 32); stageB(buf ^ 1, (kc + 1) * 32); }
    short8 a[4], bb[5];
#pragma unroll
    for (int mf = 0; mf < 4; ++mf)
      a[mf] = *(const short8*)&As[buf][(rm + mf * 16 + lr) * 32 + lk];
#pragma unroll
    for (int nf = 0; nf < 5; ++nf)
      bb[nf] = *(const short8*)&Bs[buf][(cn + nf * 16 + lr) * 32 + lk];
#pragma unroll
    for (int mf = 0; mf < 4; ++mf)
#pragma unroll
      for (int nf = 0; nf < 5; ++nf)
        acc[mf][nf] = __builtin_amdgcn_mfma_f32_16x16x32_bf16(a[mf], bb[nf], acc[mf][nf], 0, 0, 0);
    __syncthreads();
    buf ^= 1;
  }

#pragma unroll
  for (int mf = 0; mf < 4; ++mf) {
#pragma unroll
    for (int nf = 0; nf < 5; ++nf) {
      const int col = n0 + cn + nf * 16 + lr;
      float bv = 0.f;
      if (MODE < 2 && col < 300) bv = bias[col];
#pragma unroll
      for (int r = 0; r < 4; ++r) {
        const long row = m0 + rm + mf * 16 + (lane >> 4) * 4 + r;
        float v = acc[mf][nf][r] + bv;
        if (MODE == 0) {
          if (col < 300) Of[row * 300 + col] = v;
        } else if (MODE == 1) {
          unsigned short u = (col < 300) ? f2bf(v)
                            : ((col == 300) ? f2bf(1.0f) : (unsigned short)0);
          Oh[row * DP + col] = u;
        } else {
          Oh[row * DP + col] = (col <= 300) ? f2bf(v) : (unsigned short)0;
        }
      }
    }
  }
}

// ---- meanT[b][c] = (1/160) sum_l projT[b,l,c] --------------------------------
__global__ void mean_k(const float* __restrict__ projT, float* __restrict__ meanT) {
  int b = blockIdx.x, tid = threadIdx.x;
  const float* p = projT + (size_t)b * 48000;
  for (int c = tid; c < 300; c += 256) {
    float s = 0.f;
    for (int l = 0; l < 160; ++l) s += p[l * 300 + c];
    meanT[b * DP + c] = s * (1.0f / 160.0f);
  }
}

// ---- vT[b][c] = sum_a Pmat[a][c]*mT[a] + Pmat[300][c]; cT at c==300 ----------
__global__ __launch_bounds__(320)
void vt_k(const float* __restrict__ Pmat, const float* __restrict__ meanT,
          float* __restrict__ vT, float* __restrict__ cT) {
  __shared__ float mt[300];
  int b = blockIdx.x, tid = threadIdx.x;
  if (tid < 300) mt[tid] = meanT[b * DP + tid];
  __syncthreads();
  if (tid <= 300) {
    float s = 0.f;
    for (int a = 0; a < 300; ++a) s += Pmat[a * DP + tid] * mt[a];
    s += Pmat[300 * DP + tid];
    if (tid < 300) vT[b * DP + tid] = s;
    else cT[b] = s;
  }
}

// ---- ZT[b][j] = sigmoid(vT . projT_row_j + cT) -------------------------------
__global__ __launch_bounds__(256)
void zt_k(const float* __restrict__ projT, const float* __restrict__ vT,
          const float* __restrict__ cT, float* __restrict__ ZT) {
  __shared__ float v[304];
  int b = blockIdx.x, tid = threadIdx.x, wid = tid >> 6, lane = tid & 63;
  for (int c = tid; c < 300; c += 256) v[c] = vT[b * DP + c];
  if (tid == 0) v[300] = cT[b];
  __syncthreads();
  const float* p = projT + (size_t)b * 48000;
  for (int j = wid; j < 160; j += 4) {
    const float* row = p + j * 300;
    float s = 0.f;
    for (int c = lane; c < 300; c += 64) s += v[c] * row[c];
#pragma unroll
    for (int m = 1; m < 64; m <<= 1) s += __shfl_xor(s, m, 64);
    if (lane == 0) ZT[b * 160 + j] = sigm(s + v[300]);
  }
}

// ---- per-batch finale: S=Y@pCD^T, row-reduce, softmax, HCD write -------------
__global__ __launch_bounds__(320)
void finale_k(const unsigned short* __restrict__ Y, const unsigned short* __restrict__ P,
              const float* __restrict__ ZT, const float* __restrict__ W3w,
              float* __restrict__ out) {
  __shared__ __align__(16) unsigned short Ys[2][160 * 32];
  __shared__ __align__(16) unsigned short Ps[2][160 * 32];
  __shared__ float t_arr[160];
  __shared__ float s_arr[160];
  __shared__ float red0;

  const int b = blockIdx.x;
  const int tid = threadIdx.x, wid = tid >> 6, lane = tid & 63;
  const unsigned short* Yb = Y + (size_t)b * 160 * DP;
  const unsigned short* Pb = P + (size_t)b * 160 * DP;

  if (tid < 160) t_arr[tid] = ZT[b * 160 + tid] * W3w[tid];

  auto stage = [&](int buf, int k0) {
#pragma unroll
    for (int c = 0; c < 2; ++c) {
      int ch = wid + c * 5;
      int f = ch * 512 + lane * 8;
      int ro = (f >> 5) * DP + k0 + (f & 31);
      gload16(Yb + ro, &Ys[buf][ch * 512]);
      gload16(Pb + ro, &Ps[buf][ch * 512]);
    }
  };

  f32x4 acc[2][10];
#pragma unroll
  for (int i = 0; i < 2; ++i)
#pragma unroll
    for (int j = 0; j < 10; ++j) acc[i][j] = (f32x4){0.f, 0.f, 0.f, 0.f};

  stage(0, 0);
  __syncthreads();
  int buf = 0;
  const int lr = lane & 15, lk = (lane >> 4) * 8;
  const int rm = wid * 32;
  for (int kc = 0; kc < 10; ++kc) {
    if (kc < 9) stage(buf ^ 1, (kc + 1) * 32);
    short8 a[2], bb[10];
#pragma unroll
    for (int mf = 0; mf < 2; ++mf)
      a[mf] = *(const short8*)&Ys[buf][(rm + mf * 16 + lr) * 32 + lk];
#pragma unroll
    for (int nf = 0; nf < 10; ++nf)
      bb[nf] = *(const short8*)&Ps[buf][(nf * 16 + lr) * 32 + lk];
#pragma unroll
    for (int mf = 0; mf < 2; ++mf)
#pragma unroll
      for (int nf = 0; nf < 10; ++nf)
        acc[mf][nf] = __builtin_amdgcn_mfma_f32_16x16x32_bf16(a[mf], bb[nf], acc[mf][nf], 0, 0, 0);
    __syncthreads();
    buf ^= 1;
  }

  float tv[10];
#pragma unroll
  for (int nf = 0; nf < 10; ++nf) tv[nf] = t_arr[nf * 16 + lr];
  float rp[2][4];
#pragma unroll
  for (int mf = 0; mf < 2; ++mf)
#pragma unroll
    for (int r = 0; r < 4; ++r) {
      float s = 0.f;
#pragma unroll
      for (int nf = 0; nf < 10; ++nf) s += sigm(acc[mf][nf][r]) * tv[nf];
      rp[mf][r] = s;
    }
#pragma unroll
  for (int m = 1; m < 16; m <<= 1)
#pragma unroll
    for (int mf = 0; mf < 2; ++mf)
#pragma unroll
      for (int r = 0; r < 4; ++r) rp[mf][r] += __shfl_xor(rp[mf][r], m, 64);
  if (lr == 0) {
#pragma unroll
    for (int mf = 0; mf < 2; ++mf)
#pragma unroll
      for (int r = 0; r < 4; ++r)
        s_arr[rm + mf * 16 + (lane >> 4) * 4 + r] = rp[mf][r];
  }
  __syncthreads();
  if (wid == 0) {
    float v0 = s_arr[lane], v1 = s_arr[lane + 64];
    float v2 = (lane < 32) ? s_arr[lane + 128] : -3.0e38f;
    float mx = fmaxf(fmaxf(v0, v1), v2);
#pragma unroll
    for (int m = 1; m < 64; m <<= 1) mx = fmaxf(mx, __shfl_xor(mx, m, 64));
    float e0 = __expf(v0 - mx), e1 = __expf(v1 - mx);
    float e2 = (lane < 32) ? __expf(v2 - mx) : 0.f;
    s_arr[lane] = e0; s_arr[lane + 64] = e1;
    if (lane < 32) s_arr[lane + 128] = e2;
    float sm = e0 + e1 + e2;
#pragma unroll
    for (int m = 1; m < 64; m <<= 1) sm += __shfl_xor(sm, m, 64);
    if (lane == 0) red0 = 1.0f / sm;
  }
  __syncthreads();
  const float inv = red0;
  float* ob = out + (size_t)b * 48000;
  for (int e = tid; e < 48000; e += 320) {
    const int i = e / 300;
    const int c = e - i * 300;
    ob[e] = s_arr[i] * inv * bf2f(Pb[i * DP + c]);
  }
}

extern "C" void kernel_launch(void* const* d_in, const int* in_sizes, int n_in,
                              void* d_out, int out_size, void* d_ws, size_t ws_size,
                              hipStream_t stream) {
  (void)in_sizes; (void)n_in; (void)out_size; (void)ws_size;
  const float* T      = (const float*)d_in[0];
  const float* CD     = (const float*)d_in[1];
  const float* Wproj  = (const float*)d_in[2];
  const float* bproj  = (const float*)d_in[3];
  const float* WqT_w  = (const float*)d_in[4];
  const float* WqT_b  = (const float*)d_in[5];
  const float* WqCD_w = (const float*)d_in[6];
  const float* WqCD_b = (const float*)d_in[7];
  const float* WkT_w  = (const float*)d_in[8];
  const float* WkT_b  = (const float*)d_in[9];
  const float* WkCD_w = (const float*)d_in[10];
  const float* WkCD_b = (const float*)d_in[11];
  const float* W3_w   = (const float*)d_in[12];
  // W3_b unused: softmax is shift-invariant.

  char* ws = (char*)d_ws;
  size_t off = 0;
  auto alloc = [&](size_t bytes) { void* p = ws + off; off = (off + bytes + 255) & ~(size_t)255; return p; };
  unsigned short* pCD   = (unsigned short*)alloc((size_t)1024 * 160 * DP * 2);
  unsigned short* Yb    = (unsigned short*)alloc((size_t)1024 * 160 * DP * 2);
  unsigned short* Wb    = (unsigned short*)alloc((size_t)DP * DP * 2);
  unsigned short* MaugT = (unsigned short*)alloc((size_t)DP * DP * 2);
  float* Pmat  = (float*)alloc((size_t)DP * DP * 4);
  float* meanT = (float*)alloc((size_t)1024 * DP * 4);
  float* vT    = (float*)alloc((size_t)1024 * DP * 4);
  float* cT    = (float*)alloc((size_t)1024 * 4);
  float* ZT    = (float*)alloc((size_t)1024 * 160 * 4);

  float* projT = (float*)d_out;
  float* HCD   = (float*)d_out + (size_t)49152000;

  const float isd = 1.0f / sqrtf(300.0f);

  wb_k<<<dim3(320), dim3(320), 0, stream>>>(Wproj, Wb);
  // MaugT[n][c] = sum_o WqCD(c,o)*WkCD(n,o)/sqrt_d (+aug: c==300->bq, n==300->bk)
  crossdot_k<<<dim3(320), dim3(320), 0, stream>>>(WqCD_w, WqCD_b, WkCD_w, WkCD_b, MaugT, nullptr, isd);
  // Pmat[a][c] = sum_o WkT(c,o)*WqT(a,o)/sqrt_d (+aug: c==300->bkT (g), a==300->bqT (p0))
  crossdot_k<<<dim3(320), dim3(320), 0, stream>>>(WkT_w, WkT_b, WqT_w, WqT_b, nullptr, Pmat, isd);

  gemm_k<0><<<dim3(2, 640), dim3(512), 0, stream>>>(T,  nullptr, Wb, bproj, projT, nullptr);
  gemm_k<1><<<dim3(2, 640), dim3(512), 0, stream>>>(CD, nullptr, Wb, bproj, nullptr, pCD);

  mean_k<<<dim3(1024), dim3(256), 0, stream>>>(projT, meanT);
  vt_k<<<dim3(1024), dim3(320), 0, stream>>>(Pmat, meanT, vT, cT);
  zt_k<<<dim3(1024), dim3(256), 0, stream>>>(projT, vT, cT, ZT);

  gemm_k<2><<<dim3(2, 640), dim3(512), 0, stream>>>(nullptr, pCD, MaugT, nullptr, nullptr, Yb);

  finale_k<<<dim3(1024), dim3(320), 0, stream>>>(Yb, pCD, ZT, W3_w, HCD);
}

// Round 2
// 627.442 us; speedup vs baseline: 1.2330x; 1.2330x over previous
//
#include <hip/hip_runtime.h>
#include <hip/hip_bf16.h>

// B=1024, L=160, D=300. Outputs (proj_T, HCD) fp32.
// Algebra (unchanged from R1, verified absmax 0.031):
//   projT = T @ Wproj^T + b                      (fp32 out -> d_out)
//   pCD   = CD @ Wproj^T + b  (bf16, stride 320, col300=1, col>300=0)
//   vT_aug = Pmat^T mt_aug ; ZT = sigmoid(projT . vT + cT)     [gate_k]
//   Y = pCD @ MaugT^T ; S = Y @ pCD^T ; s_i = sum_j sigm(S_ij) ZT_j W3_j
//   alpha = softmax_i(s) ; HCD[i,:] = alpha_i * pCD[i,:]       [finale_k, fused]

typedef __attribute__((ext_vector_type(8))) short short8;
typedef __attribute__((ext_vector_type(4))) float f32x4;

#define DP 320

__device__ __forceinline__ unsigned short f2bf(float x) {
  unsigned int u = __builtin_bit_cast(unsigned int, x);
  u += 0x7FFFu + ((u >> 16) & 1u);
  return (unsigned short)(u >> 16);
}
__device__ __forceinline__ float bf2f(unsigned short h) {
  unsigned int u = ((unsigned int)h) << 16;
  return __builtin_bit_cast(float, u);
}
__device__ __forceinline__ void gload16(const void* g, void* l) {
  __builtin_amdgcn_global_load_lds(
      (const __attribute__((address_space(1))) unsigned int*)g,
      (__attribute__((address_space(3))) unsigned int*)l, 16, 0, 0);
}
__device__ __forceinline__ float sigm(float x) { return 1.0f / (1.0f + __expf(-x)); }
// 640B-row swizzle (40x16B groups, XOR low3 of group with row&7; bijective)
__device__ __forceinline__ int swz640(int row, int g) { return row * 640 + ((g ^ (row & 7)) << 4); }
// 128B-row swizzle for Ys
__device__ __forceinline__ int swzY(int row, int g) { return row * 128 + ((g ^ (row & 7)) << 4); }

// ---- Wb[n][k] = bf16(Wproj[n][k]), zero-padded to 320x320 --------------------
__global__ void wb_k(const float* __restrict__ W, unsigned short* __restrict__ Wb) {
  int n = blockIdx.x, k = threadIdx.x;
  unsigned short v = 0;
  if (n < 300 && k < 300) v = f2bf(W[n * 300 + k]);
  Wb[n * DP + k] = v;
}

// ---- out[n][c] = scale * sum_o A(c,o)*B(n,o); c==300 -> ba, n==300 -> bc -----
__global__ void crossdot_k(const float* __restrict__ Wa, const float* __restrict__ ba,
                           const float* __restrict__ Wc, const float* __restrict__ bc,
                           unsigned short* __restrict__ out_h, float* __restrict__ out_f,
                           float scale) {
  int n = blockIdx.x, c = threadIdx.x;
  float v = 0.f;
  if (n <= 300 && c <= 300) {
    for (int o = 0; o < 300; ++o) {
      float a = (c < 300) ? Wa[o * 300 + c] : ba[o];
      float b = (n < 300) ? Wc[o * 300 + n] : bc[o];
      v += a * b;
    }
    v *= scale;
  }
  if (out_h) out_h[n * DP + c] = f2bf(v);
  else       out_f[n * DP + c] = v;
}

// ---- main GEMM: full-N (128x320 tile). blockIdx.y: 0 -> projT fp32, 1 -> pCD bf16
__global__ __launch_bounds__(512)
void gemm_k(const float* __restrict__ Tsrc, const float* __restrict__ CDsrc,
            const unsigned short* __restrict__ Wb, const float* __restrict__ bias,
            float* __restrict__ Of, unsigned short* __restrict__ Oh) {
  __shared__ __align__(16) unsigned short As[2][128 * 40];  // padded stride 40
  __shared__ __align__(16) unsigned short Bs[2][320 * 40];
  const int tid = threadIdx.x, wid = tid >> 6, lane = tid & 63;
  const int mode = blockIdx.y;
  const float* __restrict__ A = mode ? CDsrc : Tsrc;
  const long m0 = (long)blockIdx.x * 128;
  const int lr = lane & 15, lk = (lane >> 4) * 8;
  const int rm = (wid >> 2) * 64, cn = (wid & 3) * 80;

  f32x4 acc[4][5];
#pragma unroll
  for (int i = 0; i < 4; ++i)
#pragma unroll
    for (int j = 0; j < 5; ++j) acc[i][j] = (f32x4){0.f, 0.f, 0.f, 0.f};

  auto stageA = [&](int buf, int k0) {
    const int row = tid >> 2, cg = (tid & 3) * 8;
    const float* p = A + (m0 + row) * 300 + k0 + cg;
    short8 h;
    if (k0 + cg + 8 <= 300) {
      f32x4 x0 = *(const f32x4*)p, x1 = *(const f32x4*)(p + 4);
#pragma unroll
      for (int j = 0; j < 4; ++j) { h[j] = (short)f2bf(x0[j]); h[j + 4] = (short)f2bf(x1[j]); }
    } else {
#pragma unroll
      for (int j = 0; j < 8; ++j) {
        float v = (k0 + cg + j < 300) ? p[j] : 0.f;
        h[j] = (short)f2bf(v);
      }
    }
    *(short8*)&As[buf][row * 40 + cg] = h;
  };
  auto stageB = [&](int buf, int k0) {
#pragma unroll
    for (int it = 0; it < 3; ++it) {
      int idx = tid + it * 512;
      if (idx < 1280) {
        int row = idx >> 2, cg = (idx & 3) * 8;
        short8 h = *(const short8*)(Wb + row * DP + k0 + cg);
        *(short8*)&Bs[buf][row * 40 + cg] = h;
      }
    }
  };

  stageA(0, 0); stageB(0, 0);
  __syncthreads();
  int buf = 0;
  for (int kc = 0; kc < 10; ++kc) {
    if (kc < 9) { stageA(buf ^ 1, (kc + 1) * 32); stageB(buf ^ 1, (kc + 1) * 32); }
    short8 a[4], bb[5];
#pragma unroll
    for (int mf = 0; mf < 4; ++mf)
      a[mf] = *(const short8*)&As[buf][(rm + mf * 16 + lr) * 40 + lk];
#pragma unroll
    for (int nf = 0; nf < 5; ++nf)
      bb[nf] = *(const short8*)&Bs[buf][(cn + nf * 16 + lr) * 40 + lk];
#pragma unroll
    for (int mf = 0; mf < 4; ++mf)
#pragma unroll
      for (int nf = 0; nf < 5; ++nf)
        acc[mf][nf] = __builtin_amdgcn_mfma_f32_16x16x32_bf16(a[mf], bb[nf], acc[mf][nf], 0, 0, 0);
    __syncthreads();
    buf ^= 1;
  }

#pragma unroll
  for (int mf = 0; mf < 4; ++mf)
#pragma unroll
    for (int nf = 0; nf < 5; ++nf) {
      const int col = cn + nf * 16 + lr;
      const float bv = (col < 300) ? bias[col] : 0.f;
#pragma unroll
      for (int r = 0; r < 4; ++r) {
        const long row = m0 + rm + mf * 16 + (lane >> 4) * 4 + r;
        float v = acc[mf][nf][r] + bv;
        if (mode == 0) {
          if (col < 300) Of[row * 300 + col] = v;
        } else {
          unsigned short u = (col < 300) ? f2bf(v)
                            : ((col == 300) ? f2bf(1.0f) : (unsigned short)0);
          Oh[row * DP + col] = u;
        }
      }
    }
}

// ---- gate: meanT + vT + ZT fused, one block per batch ------------------------
__global__ __launch_bounds__(320)
void gate_k(const float* __restrict__ projT, const float* __restrict__ Pmat,
            float* __restrict__ ZT) {
  __shared__ float mt[304];
  __shared__ float vv[304];
  const int b = blockIdx.x, tid = threadIdx.x, wid = tid >> 6, lane = tid & 63;
  const float* p = projT + (size_t)b * 48000;
  if (tid < 300) {
    float s = 0.f;
#pragma unroll 4
    for (int l = 0; l < 160; ++l) s += p[l * 300 + tid];
    mt[tid] = s * (1.0f / 160.0f);
  }
  __syncthreads();
  if (tid <= 300) {
    float s = Pmat[300 * DP + tid];
    for (int a = 0; a < 300; ++a) s += Pmat[a * DP + tid] * mt[a];
    vv[tid] = s;
  }
  __syncthreads();
  for (int j = wid * 32; j < wid * 32 + 32; ++j) {
    const float* row = p + j * 300;
    float s = 0.f;
    for (int c = lane; c < 300; c += 64) s += vv[c] * row[c];
#pragma unroll
    for (int m = 1; m < 64; m <<= 1) s += __shfl_xor(s, m, 64);
    if (lane == 0) ZT[b * 160 + j] = sigm(s + vv[300]);
  }
}

// ---- fused finale: pCD in LDS, Y on the fly, S-accum, softmax, HCD -----------
__global__ __launch_bounds__(640)
void finale_k(const unsigned short* __restrict__ P, const unsigned short* __restrict__ Maug,
              const float* __restrict__ ZT, const float* __restrict__ W3w,
              float* __restrict__ out) {
  __shared__ __align__(16) unsigned short Ps[160 * 320];  // swizzled, 102400 B
  __shared__ __align__(16) unsigned short Ms[32 * 320];   // swizzled, 20480 B
  __shared__ __align__(16) unsigned short Ys[160 * 64];   // swizzled, 20480 B
  __shared__ float t_arr[160];
  __shared__ float s_part[5][160];
  __shared__ float s_arr[160];
  __shared__ float red0;

  const int b = blockIdx.x, tid = threadIdx.x, wid = tid >> 6, lane = tid & 63;
  const int lr = lane & 15, hi = lane >> 4;
  const unsigned short* Pb = P + (size_t)b * 160 * DP;

  if (tid < 160) t_arr[tid] = ZT[b * 160 + tid] * W3w[tid];

  // stage Ps: linear LDS dest, pre-swizzled global source (rule 21 pattern)
#pragma unroll
  for (int it = 0; it < 10; ++it) {
    int o = it * 640 + tid;          // 16B-group linear index 0..6399
    int row = o / 40, g = o - row * 40;
    gload16(Pb + row * DP + ((g ^ (row & 7)) << 3),
            (char*)Ps + ((it * 640 + (wid << 6)) << 4));
  }
  // reg-stage Ms chunk 0
  short8 mreg[2];
  int mrow[2], mg[2];
#pragma unroll
  for (int it = 0; it < 2; ++it) {
    int idx = tid + it * 640;
    mrow[it] = idx / 40; mg[it] = idx - mrow[it] * 40;
    mreg[it] = *(const short8*)(Maug + mrow[it] * DP + mg[it] * 8);
  }
  __syncthreads();  // drains vmcnt: Ps staged, mreg loaded
#pragma unroll
  for (int it = 0; it < 2; ++it)
    *(short8*)((char*)Ms + swz640(mrow[it], mg[it])) = mreg[it];
  // preload Y-phase A-fragments (Ps persistent across all chunks)
  short8 a_pre[10];
#pragma unroll
  for (int kk = 0; kk < 10; ++kk)
    a_pre[kk] = *(const short8*)((const char*)Ps + swz640(16 * wid + lr, kk * 4 + hi));
  __syncthreads();

  f32x4 acc_s[5][2];
#pragma unroll
  for (int i = 0; i < 5; ++i)
#pragma unroll
    for (int j = 0; j < 2; ++j) acc_s[i][j] = (f32x4){0.f, 0.f, 0.f, 0.f};
  const int wm = wid / 5, wn = wid - wm * 5;

  for (int nc = 0; nc < 10; ++nc) {
    if (nc < 9) {
#pragma unroll
      for (int it = 0; it < 2; ++it)
        mreg[it] = *(const short8*)(Maug + ((nc + 1) * 32 + mrow[it]) * DP + mg[it] * 8);
    }
    // Y-compute: wave wid owns Y rows [16*wid,16*wid+16), cols 0..31 of chunk
    f32x4 accy0 = (f32x4){0.f, 0.f, 0.f, 0.f}, accy1 = accy0;
#pragma unroll
    for (int kk = 0; kk < 10; ++kk) {
      short8 b0 = *(const short8*)((const char*)Ms + swz640(lr, kk * 4 + hi));
      short8 b1 = *(const short8*)((const char*)Ms + swz640(16 + lr, kk * 4 + hi));
      accy0 = __builtin_amdgcn_mfma_f32_16x16x32_bf16(a_pre[kk], b0, accy0, 0, 0, 0);
      accy1 = __builtin_amdgcn_mfma_f32_16x16x32_bf16(a_pre[kk], b1, accy1, 0, 0, 0);
    }
    __syncthreads();
    // write Ys (bf16) + Ms for next chunk
#pragma unroll
    for (int r = 0; r < 4; ++r) {
      int row = 16 * wid + hi * 4 + r;
      int c0 = lr, c1 = 16 + lr;
      *(unsigned short*)((char*)Ys + swzY(row, c0 >> 3) + ((c0 & 7) << 1)) = f2bf(accy0[r]);
      *(unsigned short*)((char*)Ys + swzY(row, c1 >> 3) + ((c1 & 7) << 1)) = f2bf(accy1[r]);
    }
    if (nc < 9) {
#pragma unroll
      for (int it = 0; it < 2; ++it)
        *(short8*)((char*)Ms + swz640(mrow[it], mg[it])) = mreg[it];
    }
    __syncthreads();
    // S-accumulate: wave (wm,wn) owns S rows [80wm,80wm+80) x cols [32wn,32wn+32)
#pragma unroll
    for (int mf = 0; mf < 5; ++mf) {
      short8 a = *(const short8*)((const char*)Ys + swzY(80 * wm + mf * 16 + lr, hi));
#pragma unroll
      for (int nf = 0; nf < 2; ++nf) {
        short8 bv = *(const short8*)((const char*)Ps + swz640(32 * wn + nf * 16 + lr, nc * 4 + hi));
        acc_s[mf][nf] = __builtin_amdgcn_mfma_f32_16x16x32_bf16(a, bv, acc_s[mf][nf], 0, 0, 0);
      }
    }
    __syncthreads();
  }

  // row-reduce sum_j sigm(S)*t
  float tv0 = t_arr[32 * wn + lr], tv1 = t_arr[32 * wn + 16 + lr];
  float pp[5][4];
#pragma unroll
  for (int mf = 0; mf < 5; ++mf)
#pragma unroll
    for (int r = 0; r < 4; ++r)
      pp[mf][r] = sigm(acc_s[mf][0][r]) * tv0 + sigm(acc_s[mf][1][r]) * tv1;
#pragma unroll
  for (int m = 1; m < 16; m <<= 1)
#pragma unroll
    for (int mf = 0; mf < 5; ++mf)
#pragma unroll
      for (int r = 0; r < 4; ++r)
        pp[mf][r] += __shfl_xor(pp[mf][r], m, 64);
  if (lr == 0) {
#pragma unroll
    for (int mf = 0; mf < 5; ++mf)
#pragma unroll
      for (int r = 0; r < 4; ++r)
        s_part[wn][80 * wm + mf * 16 + hi * 4 + r] = pp[mf][r];
  }
  __syncthreads();
  if (tid < 160)
    s_arr[tid] = s_part[0][tid] + s_part[1][tid] + s_part[2][tid] + s_part[3][tid] + s_part[4][tid];
  __syncthreads();
  if (wid == 0) {
    float v0 = s_arr[lane], v1 = s_arr[lane + 64];
    float v2 = (lane < 32) ? s_arr[lane + 128] : -3.0e38f;
    float mx = fmaxf(fmaxf(v0, v1), v2);
#pragma unroll
    for (int m = 1; m < 64; m <<= 1) mx = fmaxf(mx, __shfl_xor(mx, m, 64));
    float e0 = __expf(v0 - mx), e1 = __expf(v1 - mx);
    float e2 = (lane < 32) ? __expf(v2 - mx) : 0.f;
    s_arr[lane] = e0; s_arr[lane + 64] = e1;
    if (lane < 32) s_arr[lane + 128] = e2;
    float sm = e0 + e1 + e2;
#pragma unroll
    for (int m = 1; m < 64; m <<= 1) sm += __shfl_xor(sm, m, 64);
    if (lane == 0) red0 = 1.0f / sm;
  }
  __syncthreads();
  const float inv = red0;
  float* ob = out + (size_t)b * 48000;
  for (int e = tid; e < 48000; e += 640) {
    int i = e / 300, c = e - i * 300;
    unsigned short pv = *(const unsigned short*)((const char*)Ps + swz640(i, c >> 3) + ((c & 7) << 1));
    ob[e] = s_arr[i] * inv * bf2f(pv);
  }
}

extern "C" void kernel_launch(void* const* d_in, const int* in_sizes, int n_in,
                              void* d_out, int out_size, void* d_ws, size_t ws_size,
                              hipStream_t stream) {
  (void)in_sizes; (void)n_in; (void)out_size; (void)ws_size;
  const float* T      = (const float*)d_in[0];
  const float* CD     = (const float*)d_in[1];
  const float* Wproj  = (const float*)d_in[2];
  const float* bproj  = (const float*)d_in[3];
  const float* WqT_w  = (const float*)d_in[4];
  const float* WqT_b  = (const float*)d_in[5];
  const float* WqCD_w = (const float*)d_in[6];
  const float* WqCD_b = (const float*)d_in[7];
  const float* WkT_w  = (const float*)d_in[8];
  const float* WkT_b  = (const float*)d_in[9];
  const float* WkCD_w = (const float*)d_in[10];
  const float* WkCD_b = (const float*)d_in[11];
  const float* W3_w   = (const float*)d_in[12];
  // W3_b unused: softmax is shift-invariant.

  char* ws = (char*)d_ws;
  size_t off = 0;
  auto alloc = [&](size_t bytes) { void* p = ws + off; off = (off + bytes + 255) & ~(size_t)255; return p; };
  unsigned short* pCD   = (unsigned short*)alloc((size_t)1024 * 160 * DP * 2);
  unsigned short* Wb    = (unsigned short*)alloc((size_t)DP * DP * 2);
  unsigned short* MaugT = (unsigned short*)alloc((size_t)DP * DP * 2);
  float* Pmat = (float*)alloc((size_t)DP * DP * 4);
  float* ZT   = (float*)alloc((size_t)1024 * 160 * 4);

  float* projT = (float*)d_out;
  float* HCD   = (float*)d_out + (size_t)49152000;

  const float isd = 1.0f / sqrtf(300.0f);

  wb_k<<<dim3(320), dim3(320), 0, stream>>>(Wproj, Wb);
  crossdot_k<<<dim3(320), dim3(320), 0, stream>>>(WqCD_w, WqCD_b, WkCD_w, WkCD_b, MaugT, nullptr, isd);
  crossdot_k<<<dim3(320), dim3(320), 0, stream>>>(WkT_w, WkT_b, WqT_w, WqT_b, nullptr, Pmat, isd);

  gemm_k<<<dim3(1280, 2), dim3(512), 0, stream>>>(T, CD, Wb, bproj, projT, pCD);
  gate_k<<<dim3(1024), dim3(320), 0, stream>>>(projT, Pmat, ZT);
  finale_k<<<dim3(1024), dim3(640), 0, stream>>>(pCD, MaugT, ZT, W3_w, HCD);
}